// Round 13
// baseline (1823.268 us; speedup 1.0000x reference)
//
#include <hip/hip_runtime.h>

#define BS 256
#define SS 1152   // per-sample stride for CUR/GbM/TM/GM
#define PSS 1584  // pool per-sample stride
#define BSS 2304  // BIGT per-sample stride

// ---------------- static schedule tables ----------------
__device__ const int g_uprev[2][6] = {{1,4,4,4,4,4},{1,4,8,8,8,4}};
__device__ const int g_dprev[2][6] = {{4,4,4,4,4,1},{4,8,8,8,4,1}};
__device__ const int g_mtab[2][5]  = {{16,16,16,16,16},{16,32,32,32,16}};
__device__ const int g_cbtab[5]    = {4,8,8,8,4};
__device__ const int g_ucurtab[5]  = {1,4,8,8,8};
__device__ const int g_dntab[2][5] = {{16,16,16,16,1},{32,32,32,16,1}};
__device__ const int g_path[2][5]  = {{0,0,1,1,2},{0,0,0,0,2}};
__device__ const int g_offtab[4][5]= {{0,128,384,640,896},
                                      {1024,1152,1664,2176,2688},
                                      {2816,2944,3456,3968,4480},
                                      {4608,4736,5248,5760,6272}};
__device__ const int g_ufin[6] = {1,4,8,8,8,4};
__device__ const int g_dfin[6] = {4,8,8,8,4,1};

// ============ kernel 1: proj[s][k] = ETA*mlp(x_s)[k] ============
__global__ __launch_bounds__(256) void mlp_kernel(
    const float* __restrict__ W1, const float* __restrict__ b1,
    const float* __restrict__ W2, const float* __restrict__ b2,
    const int* __restrict__ x, float* __restrict__ proj)
{
  __shared__ float hbuf[8][64];
  const int tid = threadIdx.x;
  const int s0 = blockIdx.x << 3;
  for (int e = tid; e < 512; e += 256) {
    const int sl = e >> 6, hh = e & 63;
    const int* xr = x + (s0 + sl) * 36;
    const float* wr = W1 + hh * 36;
    float acc = b1[hh];
    #pragma unroll
    for (int t = 0; t < 36; ++t) acc += wr[t] * (float)xr[t];
    hbuf[sl][hh] = fmaxf(acc, 0.0f);
  }
  __syncthreads();
  for (int k = tid; k < 6400; k += 256) {
    const float4* wr = (const float4*)(W2 + (size_t)k * 64);
    float acc[8];
    #pragma unroll
    for (int s2 = 0; s2 < 8; ++s2) acc[s2] = 0.0f;
    #pragma unroll
    for (int c = 0; c < 16; ++c) {
      const float4 w = wr[c];
      #pragma unroll
      for (int s2 = 0; s2 < 8; ++s2) {
        const float4 hv = ((const float4*)hbuf[s2])[c];
        acc[s2] += w.x * hv.x + w.y * hv.y + w.z * hv.z + w.w * hv.w;
      }
    }
    const float bb = b2[k];
    #pragma unroll
    for (int s2 = 0; s2 < 8; ++s2)
      proj[(size_t)(s0 + s2) * 6400 + k] = 0.001f * (acc[s2] + bb);
  }
}

// ---------------- rotation angle (HW-approx rcp/rsq/sqrt, ~1ulp) ----------------
__device__ __forceinline__ void jrot(float app, float aqq, float apq, float& c, float& sn) {
  c = 1.0f; sn = 0.0f;
  if (fabsf(apq) > 1e-36f + 1e-12f * (fabsf(app) + fabsf(aqq))) {
    const float tau = (aqq - app) * 0.5f * __builtin_amdgcn_rcpf(apq);
    const float t = copysignf(1.0f, tau) *
                    __builtin_amdgcn_rcpf(fabsf(tau) + __builtin_amdgcn_sqrtf(1.0f + tau * tau));
    c = __builtin_amdgcn_rsqf(1.0f + t * t);
    sn = t * c;
  }
}

__device__ __forceinline__ int seatof(int i, int n) {
  return (i == n - 1) ? 0 : ((i == 0) ? 1 : ((i < (n >> 1)) ? (2 * i) : (2 * (n - 1 - i) + 1)));
}
__device__ __forceinline__ int sgshift(int s, int np) {
  if (s == 0) return 0;
  if (s & 1) return (s == 2 * np - 1) ? (2 * np - 2) : (s + 2);
  return (s == 2) ? 1 : (s - 2);
}

// SEAT-SPACE pair-blocked two-sided Jacobi, TWO samples per block (Hb/Vb + SS for sample 1).
// Sweeps 5/5/3 (4 fails - R9). All per-sample math identical to R11/R12.
template<int N>
__device__ void jacobi_pb(float* __restrict__ Hb, float* __restrict__ Vb, int tid)
{
  constexpr int NP = N / 2;
  constexpr int NM1 = N - 1;
  constexpr int NL = (N == 32) ? 5 : ((N == 16) ? 4 : 2);
  constexpr int MAXSW = (N == 32) ? 5 : ((N == 16) ? 5 : 3);
  for (int e2 = tid; e2 < 2 * N * N; e2 += BS) {
    const int sm = (e2 >= N * N) ? 1 : 0;
    const int e = e2 - sm * N * N;
    const int r = e >> NL, c = e & (N - 1);
    const int i0 = (c == 0) ? NM1 : ((c == 1) ? 0 : ((c & 1) ? (NM1 - (c >> 1)) : (c >> 1)));
    Vb[sm * SS + r * 36 + c] = (r == i0) ? 1.0f : 0.0f;
  }
  __syncthreads();
  const int cp = tid & (NP - 1);
  const int q0 = 2 * cp, q1 = q0 + 1;
  const int d0 = sgshift(q0, NP), d1 = sgshift(q1, NP);

  if (N == 32) {
    const int rt = tid >> 4;                 // 0..15
    const int r0 = 2 * rt, r1 = r0 + 1;
    const int e0 = sgshift(r0, NP), e1 = sgshift(r1, NP);
    const int vrow0 = rt, vrow1 = rt + 16;
    for (int sw = 0; sw < MAXSW; ++sw)
      for (int rd = 0; rd < NM1; ++rd) {
        float c0, s0, c1, s1;
        { const float2 dg = *(const float2*)(Hb + q0 * 36 + q0);
          jrot(dg.x, Hb[q1 * 36 + q1], dg.y, c0, s0); }
        { const float2 dg = *(const float2*)(Hb + SS + q0 * 36 + q0);
          jrot(dg.x, Hb[SS + q1 * 36 + q1], dg.y, c1, s1); }
        const float cr0 = __shfl(c0, rt), sr0 = __shfl(s0, rt);
        const float cr1 = __shfl(c1, rt), sr1 = __shfl(s1, rt);
        float o[2][4], va[2][2], vb[2][2];
        #pragma unroll
        for (int sm = 0; sm < 2; ++sm) {
          const float cc_ = sm ? c1 : c0, cs_ = sm ? s1 : s0;
          const float cr_ = sm ? cr1 : cr0, sr_ = sm ? sr1 : sr0;
          const float* H = Hb + sm * SS;
          const float2 rA = *(const float2*)(H + r0 * 36 + q0);
          const float2 rB = *(const float2*)(H + r1 * 36 + q0);
          const float t1 = cr_ * rA.x - sr_ * rB.x, t2 = cr_ * rA.y - sr_ * rB.y;
          const float u1 = sr_ * rA.x + cr_ * rB.x, u2 = sr_ * rA.y + cr_ * rB.y;
          o[sm][0] = cc_ * t1 - cs_ * t2; o[sm][1] = cs_ * t1 + cc_ * t2;
          o[sm][2] = cc_ * u1 - cs_ * u2; o[sm][3] = cs_ * u1 + cc_ * u2;
          const float* V = Vb + sm * SS;
          const float2 v0 = *(const float2*)(V + vrow0 * 36 + q0);
          const float2 v1 = *(const float2*)(V + vrow1 * 36 + q0);
          va[sm][0] = cc_ * v0.x - cs_ * v0.y; va[sm][1] = cs_ * v0.x + cc_ * v0.y;
          vb[sm][0] = cc_ * v1.x - cs_ * v1.y; vb[sm][1] = cs_ * v1.x + cc_ * v1.y;
        }
        __syncthreads();
        #pragma unroll
        for (int sm = 0; sm < 2; ++sm) {
          float* H = Hb + sm * SS;
          H[e0 * 36 + d0] = o[sm][0]; H[e0 * 36 + d1] = o[sm][1];
          H[e1 * 36 + d0] = o[sm][2]; H[e1 * 36 + d1] = o[sm][3];
          float* V = Vb + sm * SS;
          V[vrow0 * 36 + d0] = va[sm][0]; V[vrow0 * 36 + d1] = va[sm][1];
          V[vrow1 * 36 + d0] = vb[sm][0]; V[vrow1 * 36 + d1] = vb[sm][1];
        }
        __syncthreads();
      }
  } else {
    const int hsm = (N == 16) ? ((tid >> 6) & 1) : ((tid >> 2) & 1);
    const bool hact = (N == 16) ? (tid < 128) : (tid < 8);
    const int rt = (N == 16) ? ((tid >> 3) & 7) : ((tid >> 1) & 1);
    const int r0 = 2 * rt, r1 = r0 + 1;
    const int e0 = sgshift(r0, NP), e1 = sgshift(r1, NP);
    const int vsm = (N == 16) ? (tid >> 7) : ((tid >> 3) & 1);
    const bool vact = (N == 16) ? true : (tid < 16);
    const int vrow = (N == 16) ? ((tid >> 3) & 15) : ((tid >> 1) & 3);
    for (int sw = 0; sw < MAXSW; ++sw)
      for (int rd = 0; rd < NM1; ++rd) {
        float c0, s0, c1, s1;
        { const float2 dg = *(const float2*)(Hb + q0 * 36 + q0);
          jrot(dg.x, Hb[q1 * 36 + q1], dg.y, c0, s0); }
        { const float2 dg = *(const float2*)(Hb + SS + q0 * 36 + q0);
          jrot(dg.x, Hb[SS + q1 * 36 + q1], dg.y, c1, s1); }
        const float cr0 = __shfl(c0, rt), sr0 = __shfl(s0, rt);
        const float cr1 = __shfl(c1, rt), sr1 = __shfl(s1, rt);
        float o0, o1, o2, o3, w0, w1;
        if (hact) {
          const float cc_ = hsm ? c1 : c0, cs_ = hsm ? s1 : s0;
          const float cr_ = hsm ? cr1 : cr0, sr_ = hsm ? sr1 : sr0;
          const float* H = Hb + hsm * SS;
          const float2 rA = *(const float2*)(H + r0 * 36 + q0);
          const float2 rB = *(const float2*)(H + r1 * 36 + q0);
          const float t1 = cr_ * rA.x - sr_ * rB.x, t2 = cr_ * rA.y - sr_ * rB.y;
          const float u1 = sr_ * rA.x + cr_ * rB.x, u2 = sr_ * rA.y + cr_ * rB.y;
          o0 = cc_ * t1 - cs_ * t2; o1 = cs_ * t1 + cc_ * t2;
          o2 = cc_ * u1 - cs_ * u2; o3 = cs_ * u1 + cc_ * u2;
        }
        if (vact) {
          const float cc_ = vsm ? c1 : c0, cs_ = vsm ? s1 : s0;
          const float2 vv = *(const float2*)(Vb + vsm * SS + vrow * 36 + q0);
          w0 = cc_ * vv.x - cs_ * vv.y;
          w1 = cs_ * vv.x + cc_ * vv.y;
        }
        __syncthreads();
        if (hact) {
          float* H = Hb + hsm * SS;
          H[e0 * 36 + d0] = o0; H[e0 * 36 + d1] = o1;
          H[e1 * 36 + d0] = o2; H[e1 * 36 + d1] = o3;
        }
        if (vact) {
          float* V = Vb + vsm * SS;
          V[vrow * 36 + d0] = w0;
          V[vrow * 36 + d1] = w1;
        }
        __syncthreads();
      }
  }
}

// G(+)= A^T A, both samples; A stride as_, G stride SS
__device__ __forceinline__ void gram_cols(float* __restrict__ G, const float* __restrict__ A,
                                          int as_, int nrows, int mcols, bool init, int tid)
{
  const int q4 = mcols >> 2;
  const int q4log = (mcols == 32) ? 3 : 2;
  const int nel = mcols * q4;
  for (int e2 = tid; e2 < 2 * nel; e2 += BS) {
    const int sm = (e2 >= nel) ? 1 : 0;
    const int e = e2 - sm * nel;
    const float* As = A + sm * as_;
    float* Gs = G + sm * SS;
    const int c2q = e & (q4 - 1);
    const int c1 = e >> q4log;
    float ax = 0.f, ay = 0.f, az = 0.f, aw = 0.f;
    for (int r = 0; r < nrows; ++r) {
      const float a1 = As[r * 36 + c1];
      const float4 a2 = *(const float4*)(As + r * 36 + c2q * 4);
      ax += a1 * a2.x; ay += a1 * a2.y; az += a1 * a2.z; aw += a1 * a2.w;
    }
    float4* gp = (float4*)(Gs + c1 * 36 + c2q * 4);
    if (init) { float4 o; o.x = ax; o.y = ay; o.z = az; o.w = aw; *gp = o; }
    else { float4 o = *gp; o.x += ax; o.y += ay; o.z += az; o.w += aw; *gp = o; }
  }
  __syncthreads();
}

// absorb site (i1,j), both samples; poolS = pool + slot*264 (sample stride PSS)
__device__ __forceinline__ void absorb_T(const float* __restrict__ Tg, const float* __restrict__ poolS,
    float* __restrict__ BIGT, float* __restrict__ ATile, const int* __restrict__ xi,
    int i1, int j, int U, int Dd, int rr0, int rr1, int tid)
{
  const int bd = (i1 == 5) ? 1 : 4;
  const int dbw = Dd * bd;
  const int mt_ = U * 4;
  const float* tb = Tg + (size_t)(i1 * 6 + j) * 512;
  for (int e2 = tid; e2 < 512; e2 += BS) {
    const int sm = e2 >> 8, e = e2 & 255;
    ATile[sm * 256 + e] = tb[e * 2 + xi[sm * 36 + i1 * 6 + j]];
  }
  __syncthreads();
  const int mlog = (mt_ == 32) ? 5 : 4;
  const int dblog = 31 - __clz(dbw);
  const int bdlog = (bd == 4) ? 2 : 0;
  const int nel = mt_ * dbw * (rr1 - rr0);
  for (int e2 = tid; e2 < 2 * nel; e2 += BS) {
    const int sm = (e2 >= nel) ? 1 : 0;
    const int e = e2 - sm * nel;
    const int ua = e & (mt_ - 1);
    const int db = (e >> mlog) & (dbw - 1);
    const int rr = rr0 + (e >> (mlog + dblog));
    const int u = ua >> 2, a = ua & 3;
    const int d_ = db >> bdlog, b = db & (bd - 1);
    const float* op = poolS + sm * PSS + u * 33 + d_;
    const float4 av = *(const float4*)(ATile + sm * 256 + a * 64 + rr * 16 + b * 4);
    BIGT[sm * BSS + ((rr - rr0) * dbw + db) * 36 + ua] =
        op[0] * av.x + op[8] * av.y + op[16] * av.z + op[24] * av.w;
  }
  __syncthreads();
}

// ============ kernel 2: TWO samples per 256-thread workgroup ============
__global__ __launch_bounds__(256, 2) void peps_kernel(
    const float* __restrict__ Tg, const int* __restrict__ x,
    float* __restrict__ proj, float* __restrict__ out)
{
  __shared__ __align__(16) float pool[2 * PSS];
  __shared__ __align__(16) float CUR[2 * SS];
  __shared__ __align__(16) float BIGT[2 * BSS];
  __shared__ __align__(16) float GbM[2 * SS];
  __shared__ __align__(16) float TM[2 * SS];
  __shared__ __align__(16) float GM[2 * SS];
  __shared__ __align__(16) float ATile[2 * 256];
  __shared__ __align__(16) float PdL[2 * 256], PuL[2 * 256];
  __shared__ float red[2];
  __shared__ int isel[2 * 8];
  __shared__ float sinvv[2 * 8], sdiv[2 * 8];
  __shared__ int xi[2 * 36];
  __shared__ float vvec[2 * 36], vvec2[2 * 36];

  const int s0 = blockIdx.x * 2;
  const int tid = threadIdx.x;
  if (tid < 72) xi[tid] = x[s0 * 36 + tid];
  __syncthreads();

  for (int sweep = 0; sweep < 2; ++sweep) {
    // --- init boundary MPS from row j=0, both samples ---
    for (int i2 = 0; i2 < 6; ++i2) {
      const int ad = (i2 == 0) ? 1 : 4, bd = (i2 == 5) ? 1 : 4;
      const int bdlog = (bd == 4) ? 2 : 0;
      const float* tb = Tg + (size_t)(i2 * 6) * 512;
      const int nel = ad * 4 * bd;
      for (int e2 = tid; e2 < 2 * nel; e2 += BS) {
        const int sm = (e2 >= nel) ? 1 : 0;
        const int e = e2 - sm * nel;
        const int ph = xi[sm * 36 + i2 * 6];
        const int b = e & (bd - 1);
        const int rr = (e >> bdlog) & 3;
        const int a = e >> (bdlog + 2);
        pool[sm * PSS + i2 * 264 + a * 33 + rr * 8 + b] = tb[(a * 64 + rr * 16 + b * 4) * 2 + ph];
      }
    }
    __syncthreads();

    for (int j = 1; j <= 4; ++j) {
      const int jj = (j > 1) ? 1 : 0;
      // absorb site (0,j) into CUR (4 x 16), both samples
      {
        const float* tb = Tg + (size_t)j * 512;
        for (int e2 = tid; e2 < 512; e2 += BS) {
          const int sm = e2 >> 8, e = e2 & 255;
          ATile[sm * 256 + e] = tb[e * 2 + xi[sm * 36 + j]];
        }
        __syncthreads();
        for (int e2 = tid; e2 < 128; e2 += BS) {
          const int sm = e2 >= 64 ? 1 : 0;
          const int e = e2 & 63;
          const int db = e & 15, rr = e >> 4;
          const int d_ = db >> 2, b = db & 3;
          const float* op = pool + sm * PSS + d_;
          const float4 av = *(const float4*)(ATile + sm * 256 + rr * 16 + b * 4);
          CUR[sm * SS + rr * 36 + db] = op[0] * av.x + op[8] * av.y + op[16] * av.z + op[24] * av.w;
        }
        __syncthreads();
      }

      for (int i = 0; i < 5; ++i) {
        const int m = g_mtab[jj][i], cb = g_cbtab[i], ucur = g_ucurtab[i], dn = g_dntab[jj][i];
        const int p = ucur * 4, path = g_path[jj][i];
        const int U1 = g_uprev[jj][i + 1], Dd1 = g_dprev[jj][i + 1];
        const bool two = (dn == 32);
        const int cblog = (cb == 8) ? 3 : 2;
        const int mq4 = m >> 2;
        const int offv = g_offtab[j - 1][i];

        if (sweep == 0) {
          if (path == 2) {
            // ---- q-side: G = mb^T Gt mb (4x4), seat write ----
            absorb_T(Tg, pool + (i + 1) * 264, BIGT, ATile, xi, i + 1, j, U1, Dd1, 0, 4, tid);
            gram_cols(GbM, CUR, SS, p, m, true, tid);   // Gt (16x16)
            for (int e2 = tid; e2 < 128; e2 += BS) {    // T1 = Gt*mb (16x4)
              const int sm = e2 >= 64 ? 1 : 0;
              const int e = e2 & 63;
              const int r = e & 3, k = e >> 2;
              float acc = 0.f;
              for (int lq = 0; lq < 4; ++lq) {
                const float4 g = *(const float4*)(GbM + sm * SS + k * 36 + lq * 4);
                const float4 b = *(const float4*)(BIGT + sm * BSS + r * 36 + lq * 4);
                acc += g.x * b.x + g.y * b.y + g.z * b.z + g.w * b.w;
              }
              TM[sm * SS + k * 36 + r] = acc;
            }
            __syncthreads();
            for (int e2 = tid; e2 < 32; e2 += BS) {     // G = mb^T*T1 (4x4)
              const int sm = e2 >= 16 ? 1 : 0;
              const int e = e2 & 15;
              const int c = e & 3, r = e >> 2;
              float acc = 0.f;
              for (int k = 0; k < 16; ++k)
                acc += BIGT[sm * BSS + r * 36 + k] * TM[sm * SS + k * 36 + c];
              GM[sm * SS + seatof(r, 4) * 36 + seatof(c, 4)] = acc;
            }
            __syncthreads();
            jacobi_pb<4>(GM, TM + 576, tid);
          } else if (path == 0) {
            // ---- p-side: G = mt Gb mt^T (p x p), seat write ----
            if (!two) {
              absorb_T(Tg, pool + (i + 1) * 264, BIGT, ATile, xi, i + 1, j, U1, Dd1, 0, 4, tid);
              gram_cols(GbM, BIGT, BSS, 4 * dn, m, true, tid);
            } else {
              absorb_T(Tg, pool + (i + 1) * 264, BIGT, ATile, xi, i + 1, j, U1, Dd1, 0, 2, tid);
              gram_cols(GbM, BIGT, BSS, 2 * dn, m, true, tid);
              absorb_T(Tg, pool + (i + 1) * 264, BIGT, ATile, xi, i + 1, j, U1, Dd1, 2, 4, tid);
              gram_cols(GbM, BIGT, BSS, 2 * dn, m, false, tid);
            }
            const int q4log = (m == 32) ? 3 : 2;
            const int nel1 = p * mq4;
            for (int e2 = tid; e2 < 2 * nel1; e2 += BS) {  // T = mt*Gb (p x m)
              const int sm = (e2 >= nel1) ? 1 : 0;
              const int e = e2 - sm * nel1;
              const int lq = e & (mq4 - 1), pr = e >> q4log;
              float ax = 0.f, ay = 0.f, az = 0.f, aw = 0.f;
              for (int k = 0; k < m; ++k) {
                const float a1 = CUR[sm * SS + pr * 36 + k];
                const float4 g = *(const float4*)(GbM + sm * SS + k * 36 + lq * 4);
                ax += a1 * g.x; ay += a1 * g.y; az += a1 * g.z; aw += a1 * g.w;
              }
              float4 o; o.x = ax; o.y = ay; o.z = az; o.w = aw;
              *(float4*)(TM + sm * SS + pr * 36 + lq * 4) = o;
            }
            __syncthreads();
            const int plog = (p == 32) ? 5 : ((p == 16) ? 4 : 2);
            const int nel2 = p * p;
            for (int e2 = tid; e2 < 2 * nel2; e2 += BS) {  // G = T*mt^T (p x p)
              const int sm = (e2 >= nel2) ? 1 : 0;
              const int e = e2 - sm * nel2;
              const int pc = e & (p - 1), pr = e >> plog;
              float acc = 0.f;
              for (int lq = 0; lq < mq4; ++lq) {
                const float4 t = *(const float4*)(TM + sm * SS + pr * 36 + lq * 4);
                const float4 c = *(const float4*)(CUR + sm * SS + pc * 36 + lq * 4);
                acc += t.x * c.x + t.y * c.y + t.z * c.z + t.w * c.w;
              }
              GM[sm * SS + seatof(pr, p) * 36 + seatof(pc, p)] = acc;
            }
            __syncthreads();
            if (p == 4)       jacobi_pb<4>(GM, TM, tid);
            else if (p == 16) jacobi_pb<16>(GM, TM, tid);
            else              jacobi_pb<32>(GM, TM, tid);
          } else {
            // ---- m-side: Gt, Gb, chol(Gb)->R2, H = R2 Gt R2^T (16x16), seat write ----
            absorb_T(Tg, pool + (i + 1) * 264, BIGT, ATile, xi, i + 1, j, U1, Dd1, 0, 4, tid);
            gram_cols(GbM + 576, CUR, SS, p, m, true, tid);      // Gt
            gram_cols(GbM, BIGT, BSS, 4 * dn, m, true, tid);     // Gb
            if (tid < 128) {  // max diag per sample (wave0/wave1)
              const int sm = tid >> 6, l = tid & 63;
              float v_ = (l < 16) ? GbM[sm * SS + l * 37] : -3.0e38f;
              for (int mk = 32; mk; mk >>= 1) v_ = fmaxf(v_, __shfl_xor(v_, mk));
              if (l == 0) red[sm] = v_;
            }
            __syncthreads();
            for (int k = 0; k < 16; ++k) {
              if (tid < 32) {
                const int sm = tid >> 4, col = tid & 15;
                const float thr = 1e-10f * red[sm] + 1e-35f;
                const float dk = GbM[sm * SS + k * 37];
                const float rs = (dk > thr) ? (1.0f / sqrtf(dk)) : 0.0f;
                TM[sm * SS + k * 36 + col] = GbM[sm * SS + k * 36 + col] * rs;
              }
              __syncthreads();
              const int rows = 15 - k;
              for (int e2 = tid; e2 < 2 * rows * 16; e2 += BS) {
                const int sm = (e2 >= rows * 16) ? 1 : 0;
                const int e = e2 - sm * rows * 16;
                const int ii = k + 1 + (e >> 4), jc = e & 15;
                GbM[sm * SS + ii * 36 + jc] -= TM[sm * SS + k * 36 + ii] * TM[sm * SS + k * 36 + jc];
              }
              __syncthreads();
            }
            for (int e2 = tid; e2 < 128; e2 += BS) {   // T1 = R2*Gt -> TM+576
              const int sm = e2 >= 64 ? 1 : 0;
              const int e = e2 & 63;
              const int jq = e & 3, k = e >> 2;
              float ax = 0.f, ay = 0.f, az = 0.f, aw = 0.f;
              for (int l = 0; l < 16; ++l) {
                const float r2 = TM[sm * SS + k * 36 + l];
                const float4 g = *(const float4*)(GbM + sm * SS + 576 + l * 36 + jq * 4);
                ax += r2 * g.x; ay += r2 * g.y; az += r2 * g.z; aw += r2 * g.w;
              }
              float4 o; o.x = ax; o.y = ay; o.z = az; o.w = aw;
              *(float4*)(TM + sm * SS + 576 + k * 36 + jq * 4) = o;
            }
            __syncthreads();
            for (int e2 = tid; e2 < 512; e2 += BS) {   // H = T1*R2^T -> GM (seat)
              const int sm = e2 >= 256 ? 1 : 0;
              const int e = e2 & 255;
              const int k2 = e & 15, k = e >> 4;
              float acc = 0.f;
              for (int lq = 0; lq < 4; ++lq) {
                const float4 t = *(const float4*)(TM + sm * SS + 576 + k * 36 + lq * 4);
                const float4 r = *(const float4*)(TM + sm * SS + k2 * 36 + lq * 4);
                acc += t.x * r.x + t.y * r.y + t.z * r.z + t.w * r.w;
              }
              GM[sm * SS + seatof(k, 16) * 36 + seatof(k2, 16)] = acc;
            }
            __syncthreads();
            jacobi_pb<16>(GM, TM + 576, tid);
          }

          // ---- top-cb selection + scales, per sample (wave0/wave1) ----
          const int N = (path == 2) ? 4 : ((path == 1) ? 16 : p);
          if (tid < 128) {
            const int sm = tid >> 6, l = tid & 63;
            float v_ = (l < N) ? GM[sm * SS + l * 37] : -3.0e38f;
            int ix = l;
            for (int t = 0; t < cb; ++t) {
              float bv = v_; int bi = ix;
              for (int mk = 32; mk; mk >>= 1) {
                const float ov = __shfl_xor(bv, mk);
                const int oi = __shfl_xor(bi, mk);
                if (ov > bv || (ov == bv && oi < bi)) { bv = ov; bi = oi; }
              }
              if (l == 0) isel[sm * 8 + t] = bi;
              if (ix == bi) v_ = -3.0e38f;
            }
          }
          __syncthreads();
          if (tid < 2 * cb) {
            const int sm = (tid >= cb) ? 1 : 0;
            const int k = tid - sm * cb;
            const float lam = GM[sm * SS + isel[sm * 8 + k] * 37];
            const float s_ = sqrtf(fmaxf(lam, 0.0f));
            sinvv[sm * 8 + k] = 1.0f / sqrtf(s_ + 1e-12f);
            sdiv[sm * 8 + k] = 1.0f / fmaxf(s_, 1e-25f);
          }
          __syncthreads();

          // ---- projectors ----
          const int mcb = m * cb;
          if (path == 0) {
            for (int e2 = tid; e2 < 2 * mcb; e2 += BS) {  // Pu = mt^T U sinv
              const int sm = (e2 >= mcb) ? 1 : 0;
              const int e = e2 - sm * mcb;
              const int k = e & (cb - 1), mrow = e >> cblog;
              const int a = isel[sm * 8 + k];
              float acc = 0.f;
              for (int pr = 0; pr < p; ++pr)
                acc += CUR[sm * SS + pr * 36 + mrow] * TM[sm * SS + pr * 36 + a];
              PuL[sm * 256 + mrow * 8 + k] = acc * sinvv[sm * 8 + k];
            }
            __syncthreads();
            for (int e2 = tid; e2 < 2 * mcb; e2 += BS) {  // Pd = Gb Pu / s
              const int sm = (e2 >= mcb) ? 1 : 0;
              const int e = e2 - sm * mcb;
              const int k = e & (cb - 1), mrow = e >> cblog;
              float acc = 0.f;
              for (int l = 0; l < m; ++l)
                acc += GbM[sm * SS + mrow * 36 + l] * PuL[sm * 256 + l * 8 + k];
              PdL[sm * 256 + mrow * 8 + k] = acc * sdiv[sm * 8 + k];
            }
            __syncthreads();
          } else if (path == 2) {
            for (int e2 = tid; e2 < 2 * mcb; e2 += BS) {  // Pd = mb V sinv
              const int sm = (e2 >= mcb) ? 1 : 0;
              const int e = e2 - sm * mcb;
              const int k = e & (cb - 1), mrow = e >> cblog;
              const int a = isel[sm * 8 + k];
              float acc = 0.f;
              for (int r = 0; r < 4; ++r)
                acc += BIGT[sm * BSS + r * 36 + mrow] * TM[sm * SS + 576 + r * 36 + a];
              PdL[sm * 256 + mrow * 8 + k] = acc * sinvv[sm * 8 + k];
            }
            __syncthreads();
            for (int e2 = tid; e2 < 2 * mcb; e2 += BS) {  // Pu = Gt Pd / s
              const int sm = (e2 >= mcb) ? 1 : 0;
              const int e = e2 - sm * mcb;
              const int k = e & (cb - 1), mrow = e >> cblog;
              float acc = 0.f;
              for (int l = 0; l < m; ++l)
                acc += GbM[sm * SS + mrow * 36 + l] * PdL[sm * 256 + l * 8 + k];
              PuL[sm * 256 + mrow * 8 + k] = acc * sdiv[sm * 8 + k];
            }
            __syncthreads();
          } else {
            for (int e2 = tid; e2 < 2 * mcb; e2 += BS) {  // Pd = R2^T V sinv
              const int sm = (e2 >= mcb) ? 1 : 0;
              const int e = e2 - sm * mcb;
              const int k = e & (cb - 1), mrow = e >> cblog;
              const int a = isel[sm * 8 + k];
              float acc = 0.f;
              for (int t = 0; t < 16; ++t)
                acc += TM[sm * SS + t * 36 + mrow] * TM[sm * SS + 576 + t * 36 + a];
              PdL[sm * 256 + mrow * 8 + k] = acc * sinvv[sm * 8 + k];
            }
            __syncthreads();
            for (int e2 = tid; e2 < 2 * mcb; e2 += BS) {  // Pu = Gt Pd / s
              const int sm = (e2 >= mcb) ? 1 : 0;
              const int e = e2 - sm * mcb;
              const int k = e & (cb - 1), mrow = e >> cblog;
              float acc = 0.f;
              for (int l = 0; l < m; ++l)
                acc += GbM[sm * SS + 576 + mrow * 36 + l] * PdL[sm * 256 + l * 8 + k];
              PuL[sm * 256 + mrow * 8 + k] = acc * sdiv[sm * 8 + k];
            }
            __syncthreads();
          }
          // store perturbed projectors
          for (int e2 = tid; e2 < 2 * mcb; e2 += BS) {
            const int sm = (e2 >= mcb) ? 1 : 0;
            const int e = e2 - sm * mcb;
            proj[(size_t)(s0 + sm) * 6400 + offv + e] += PdL[sm * 256 + (e >> cblog) * 8 + (e & (cb - 1))];
          }
          for (int e2 = tid; e2 < 2 * mcb; e2 += BS) {
            const int sm = (e2 >= mcb) ? 1 : 0;
            const int e = e2 - sm * mcb;
            proj[(size_t)(s0 + sm) * 6400 + offv + mcb + e] += PuL[sm * 256 + (e >> cblog) * 8 + (e & (cb - 1))];
          }
        } else {
          // ---- sweep 2: load perturbed projectors + stage mb ----
          const int mcb = m * cb;
          for (int e2 = tid; e2 < 2 * mcb; e2 += BS) {
            const int sm = (e2 >= mcb) ? 1 : 0;
            const int e = e2 - sm * mcb;
            PdL[sm * 256 + (e >> cblog) * 8 + (e & (cb - 1))] = proj[(size_t)(s0 + sm) * 6400 + offv + e];
          }
          for (int e2 = tid; e2 < 2 * mcb; e2 += BS) {
            const int sm = (e2 >= mcb) ? 1 : 0;
            const int e = e2 - sm * mcb;
            PuL[sm * 256 + (e >> cblog) * 8 + (e & (cb - 1))] = proj[(size_t)(s0 + sm) * 6400 + offv + mcb + e];
          }
          __syncthreads();
          if (!two) absorb_T(Tg, pool + (i + 1) * 264, BIGT, ATile, xi, i + 1, j, U1, Dd1, 0, 4, tid);
          else      absorb_T(Tg, pool + (i + 1) * 264, BIGT, ATile, xi, i + 1, j, U1, Dd1, 2, 4, tid);
        }

        // ---- common: bn0 -> pool[i]; bn1 -> CUR (or pool[5]) ----
        {
          const int nel = ucur * 4 * cb;
          for (int e2 = tid; e2 < 2 * nel; e2 += BS) {
            const int sm = (e2 >= nel) ? 1 : 0;
            const int e = e2 - sm * nel;
            const int cc = e & (cb - 1);
            const int rr = (e >> cblog) & 3;
            const int u = e >> (cblog + 2);
            const int row = u * 4 + rr;
            float acc = 0.f;
            for (int mq = 0; mq < mq4; ++mq) {
              const float4 cv = *(const float4*)(CUR + sm * SS + row * 36 + mq * 4);
              acc += cv.x * PdL[sm * 256 + (mq * 4 + 0) * 8 + cc] + cv.y * PdL[sm * 256 + (mq * 4 + 1) * 8 + cc]
                   + cv.z * PdL[sm * 256 + (mq * 4 + 2) * 8 + cc] + cv.w * PdL[sm * 256 + (mq * 4 + 3) * 8 + cc];
            }
            pool[sm * PSS + i * 264 + u * 33 + rr * 8 + cc] = acc;
          }
          __syncthreads();

          const int dnlog = 31 - __clz(dn);
          auto bn1 = [&](int rr0, int nloc) {
            const int ne2 = cb * nloc * dn;
            for (int e2 = tid; e2 < 2 * ne2; e2 += BS) {
              const int sm = (e2 >= ne2) ? 1 : 0;
              const int e = e2 - sm * ne2;
              const int dd = e & (dn - 1);
              const int t = e >> dnlog;
              const int rrL = t & (nloc - 1);
              const int cc = t >> ((nloc == 4) ? 2 : 1);
              const int row = rrL * dn + dd;
              float acc = 0.f;
              for (int mq = 0; mq < mq4; ++mq) {
                const float4 bv = *(const float4*)(BIGT + sm * BSS + row * 36 + mq * 4);
                acc += bv.x * PuL[sm * 256 + (mq * 4 + 0) * 8 + cc] + bv.y * PuL[sm * 256 + (mq * 4 + 1) * 8 + cc]
                     + bv.z * PuL[sm * 256 + (mq * 4 + 2) * 8 + cc] + bv.w * PuL[sm * 256 + (mq * 4 + 3) * 8 + cc];
              }
              if (i < 4) CUR[sm * SS + (cc * 4 + rr0 + rrL) * 36 + dd] = acc;
              else       pool[sm * PSS + 5 * 264 + cc * 33 + (rr0 + rrL) * 8] = acc;
            }
            __syncthreads();
          };
          if (!two) {
            bn1(0, 4);
          } else {
            bn1(2, 2);
            absorb_T(Tg, pool + (i + 1) * 264, BIGT, ATile, xi, i + 1, j, U1, Dd1, 0, 2, tid);
            bn1(0, 2);
          }
        }
      }
    }

    if (sweep == 1) {
      // ---- finalize: scalar = prod_i C_i, both samples ----
      if (tid < 2) vvec[tid * 36] = 1.0f;
      __syncthreads();
      for (int i = 0; i < 6; ++i) {
        const int ad = (i == 0) ? 1 : 4, bd = (i == 5) ? 1 : 4;
        const int adlog = (ad == 4) ? 2 : 0, bdlog = (bd == 4) ? 2 : 0;
        const int rows = g_ufin[i] * ad, cols = g_dfin[i] * bd;
        const int clog = 31 - __clz(cols);
        const float* tb = Tg + (size_t)(i * 6 + 5) * 512;
        for (int e2 = tid; e2 < 512; e2 += BS) {
          const int sm = e2 >> 8, e = e2 & 255;
          ATile[sm * 256 + e] = tb[e * 2 + xi[sm * 36 + i * 6 + 5]];
        }
        __syncthreads();
        const int nel = rows * cols;
        for (int e2 = tid; e2 < 2 * nel; e2 += BS) {
          const int sm = (e2 >= nel) ? 1 : 0;
          const int e = e2 - sm * nel;
          const int col = e & (cols - 1);
          const int ua = e >> clog;
          const int u = ua >> adlog, a = ua & (ad - 1);
          const int d_ = col >> bdlog, b = col & (bd - 1);
          const float* fb = pool + sm * PSS + i * 264 + u * 33 + d_;
          const float4 av = *(const float4*)(ATile + sm * 256 + a * 64 + b * 4);  // R = 0 slice
          GM[sm * SS + ua * 36 + col] = fb[0] * av.x + fb[8] * av.y + fb[16] * av.z + fb[24] * av.w;
        }
        __syncthreads();
        if (tid < 2 * cols) {
          const int sm = (tid >= cols) ? 1 : 0;
          const int c = tid - sm * cols;
          float acc = 0.f;
          for (int r_ = 0; r_ < rows; ++r_) acc += vvec[sm * 36 + r_] * GM[sm * SS + r_ * 36 + c];
          vvec2[sm * 36 + c] = acc;
        }
        __syncthreads();
        if (tid < 2 * cols) {
          const int sm = (tid >= cols) ? 1 : 0;
          const int c = tid - sm * cols;
          vvec[sm * 36 + c] = vvec2[sm * 36 + c];
        }
        __syncthreads();
      }
      if (tid < 2) out[s0 + tid] = vvec[tid * 36];
    }
  }
}

extern "C" void kernel_launch(void* const* d_in, const int* in_sizes, int n_in,
                              void* d_out, int out_size, void* d_ws, size_t ws_size,
                              hipStream_t stream) {
  const float* Tg = (const float*)d_in[0];
  const float* W1 = (const float*)d_in[1];
  const float* b1 = (const float*)d_in[2];
  const float* W2 = (const float*)d_in[3];
  const float* b2 = (const float*)d_in[4];
  const int*   x  = (const int*)d_in[5];
  float* out = (float*)d_out;
  float* proj = (float*)d_ws;   // 1024*6400 floats: ETA*mlp then += projectors
  (void)in_sizes; (void)n_in; (void)out_size; (void)ws_size;

  mlp_kernel<<<dim3(128), dim3(256), 0, stream>>>(W1, b1, W2, b2, x, proj);
  peps_kernel<<<dim3(512), dim3(256), 0, stream>>>(Tg, x, proj, out);
}

// Round 14
// 1358.295 us; speedup vs baseline: 1.3423x; 1.3423x over previous
//
#include <hip/hip_runtime.h>

#define BS 256  // threads per peps block (4 waves)

// ---------------- static schedule tables ----------------
__device__ const int g_uprev[2][6] = {{1,4,4,4,4,4},{1,4,8,8,8,4}};
__device__ const int g_dprev[2][6] = {{4,4,4,4,4,1},{4,8,8,8,4,1}};
__device__ const int g_mtab[2][5]  = {{16,16,16,16,16},{16,32,32,32,16}};
__device__ const int g_cbtab[5]    = {4,8,8,8,4};
__device__ const int g_ucurtab[5]  = {1,4,8,8,8};
__device__ const int g_dntab[2][5] = {{16,16,16,16,1},{32,32,32,16,1}};
__device__ const int g_path[2][5]  = {{0,0,1,1,2},{0,0,0,0,2}};  // 0=p-side,1=m-side(chol),2=q-side
__device__ const int g_offtab[4][5]= {{0,128,384,640,896},
                                      {1024,1152,1664,2176,2688},
                                      {2816,2944,3456,3968,4480},
                                      {4608,4736,5248,5760,6272}};
__device__ const int g_ufin[6] = {1,4,8,8,8,4};
__device__ const int g_dfin[6] = {4,8,8,8,4,1};

// ============ kernel 1: proj[s][k] = ETA*mlp(x_s)[k] ============
__global__ __launch_bounds__(256) void mlp_kernel(
    const float* __restrict__ W1, const float* __restrict__ b1,
    const float* __restrict__ W2, const float* __restrict__ b2,
    const int* __restrict__ x, float* __restrict__ proj)
{
  __shared__ float hbuf[8][64];
  const int tid = threadIdx.x;
  const int s0 = blockIdx.x << 3;
  for (int e = tid; e < 512; e += 256) {
    const int sl = e >> 6, hh = e & 63;
    const int* xr = x + (s0 + sl) * 36;
    const float* wr = W1 + hh * 36;
    float acc = b1[hh];
    #pragma unroll
    for (int t = 0; t < 36; ++t) acc += wr[t] * (float)xr[t];
    hbuf[sl][hh] = fmaxf(acc, 0.0f);
  }
  __syncthreads();
  for (int k = tid; k < 6400; k += 256) {
    const float4* wr = (const float4*)(W2 + (size_t)k * 64);
    float acc[8];
    #pragma unroll
    for (int s2 = 0; s2 < 8; ++s2) acc[s2] = 0.0f;
    #pragma unroll
    for (int c = 0; c < 16; ++c) {
      const float4 w = wr[c];
      #pragma unroll
      for (int s2 = 0; s2 < 8; ++s2) {
        const float4 hv = ((const float4*)hbuf[s2])[c];
        acc[s2] += w.x * hv.x + w.y * hv.y + w.z * hv.z + w.w * hv.w;
      }
    }
    const float bb = b2[k];
    #pragma unroll
    for (int s2 = 0; s2 < 8; ++s2)
      proj[(size_t)(s0 + s2) * 6400 + k] = 0.001f * (acc[s2] + bb);
  }
}

// ---------------- rotation angle (HW-approx rcp/rsq/sqrt, ~1ulp) ----------------
__device__ __forceinline__ void jrot(float app, float aqq, float apq, float& c, float& sn) {
  c = 1.0f; sn = 0.0f;
  if (fabsf(apq) > 1e-36f + 1e-12f * (fabsf(app) + fabsf(aqq))) {
    const float tau = (aqq - app) * 0.5f * __builtin_amdgcn_rcpf(apq);
    const float t = copysignf(1.0f, tau) *
                    __builtin_amdgcn_rcpf(fabsf(tau) + __builtin_amdgcn_sqrtf(1.0f + tau * tau));
    c = __builtin_amdgcn_rsqf(1.0f + t * t);
    sn = t * c;
  }
}

// seat of matrix index i at round 0: i==n-1 -> 0; i==0 -> 1; i<n/2 -> 2i; else 2(n-1-i)+1
__device__ __forceinline__ int seatof(int i, int n) {
  return (i == n - 1) ? 0 : ((i == 0) ? 1 : ((i < (n >> 1)) ? (2 * i) : (2 * (n - 1 - i) + 1)));
}

// tournament seat shift: 0->0; odd s: s+2 (wrap 2NP-1 -> 2NP-2); even s: s-2 (2 -> 1)
__device__ __forceinline__ int sgshift(int s, int np) {
  if (s == 0) return 0;
  if (s & 1) return (s == 2 * np - 1) ? (2 * np - 2) : (s + 2);
  return (s == 2) ? 1 : (s - 2);
}

// SEAT-SPACE pair-blocked two-sided Jacobi, 256 threads. H seat-indexed (stride 36):
// pair t = seats (2t,2t+1); N=32 -> 256 H-blocks (1/lane), V 512 slots (2/lane).
// V rows = G-space, cols = seats; init V = round-0 permutation. Sweeps 5/5/3 (4 fails - R9).
template<int N>
__device__ void jacobi_pb(float* __restrict__ H, float* __restrict__ V, int tid)
{
  constexpr int NP = N / 2;
  constexpr int NM1 = N - 1;
  constexpr int NL = (N == 32) ? 5 : ((N == 16) ? 4 : 2);
  constexpr int NVMAX = (N == 32) ? 2 : 1;
  constexpr int MAXSW = (N == 32) ? 5 : ((N == 16) ? 5 : 3);
  // V init: V[g][seat] = (g == idx0(seat))
  for (int e = tid; e < N * N; e += BS) {
    const int r = e >> NL, c = e & (N - 1);
    const int i0 = (c == 0) ? NM1 : ((c == 1) ? 0 : ((c & 1) ? (NM1 - (c >> 1)) : (c >> 1)));
    V[r * 36 + c] = (r == i0) ? 1.0f : 0.0f;
  }
  __syncthreads();
  const int cp = tid & (NP - 1);
  const bool hact = (N == 32) ? true : ((N == 16) ? (tid < 64) : (tid < 4));
  const bool vact = (N == 32) ? true : ((N == 16) ? (tid < 128) : (tid < 8));
  const int q0 = 2 * cp, q1 = q0 + 1;
  const int d0 = sgshift(q0, NP), d1 = sgshift(q1, NP);
  const int rt = (N == 32) ? (tid >> 4) : ((N == 16) ? (tid >> 3) : (tid >> 1));
  const int r0 = 2 * rt, r1 = r0 + 1;
  const int e0 = sgshift(r0, NP), e1 = sgshift(r1, NP);
  int vr[NVMAX];
  #pragma unroll
  for (int vi = 0; vi < NVMAX; ++vi)
    vr[vi] = ((N == 32) ? (tid >> 4) : ((N == 16) ? (tid >> 3) : (tid >> 1))) + NP * vi;

  for (int sw = 0; sw < MAXSW; ++sw) {
    for (int rd = 0; rd < NM1; ++rd) {
      // my column-pair angle (lane cp of each wave computes pair cp's angle)
      const float2 dg = *(const float2*)(H + q0 * 36 + q0);
      const float aqq = H[q1 * 36 + q1];
      float cc_, cs_;
      jrot(dg.x, aqq, dg.y, cc_, cs_);
      float o00, o01, o10, o11;
      if (hact) {
        const float cr_ = __shfl(cc_, rt);
        const float sr_ = __shfl(cs_, rt);
        const float2 rA = *(const float2*)(H + r0 * 36 + q0);
        const float2 rB = *(const float2*)(H + r1 * 36 + q0);
        const float t1 = cr_ * rA.x - sr_ * rB.x, t2 = cr_ * rA.y - sr_ * rB.y;
        const float u1 = sr_ * rA.x + cr_ * rB.x, u2 = sr_ * rA.y + cr_ * rB.y;
        o00 = cc_ * t1 - cs_ * t2; o01 = cs_ * t1 + cc_ * t2;
        o10 = cc_ * u1 - cs_ * u2; o11 = cs_ * u1 + cc_ * u2;
      }
      float v0[NVMAX], v1[NVMAX];
      #pragma unroll
      for (int vi = 0; vi < NVMAX; ++vi) {
        if (vi == 0 && !vact) continue;
        const float2 vv = *(const float2*)(V + vr[vi] * 36 + q0);
        v0[vi] = cc_ * vv.x - cs_ * vv.y;
        v1[vi] = cs_ * vv.x + cc_ * vv.y;
      }
      __syncthreads();
      if (hact) {
        H[e0 * 36 + d0] = o00; H[e0 * 36 + d1] = o01;
        H[e1 * 36 + d0] = o10; H[e1 * 36 + d1] = o11;
      }
      #pragma unroll
      for (int vi = 0; vi < NVMAX; ++vi) {
        if (vi == 0 && !vact) continue;
        V[vr[vi] * 36 + d0] = v0[vi];
        V[vr[vi] * 36 + d1] = v1[vi];
      }
      __syncthreads();
    }
  }
}

// G(+)= A^T A over 'nrows' stride-36 rows of A, mcols in {16,32}; float4 on column quads
__device__ __forceinline__ void gram_cols(float* __restrict__ G, const float* __restrict__ A,
                                          int nrows, int mcols, bool init, int tid)
{
  const int q4 = mcols >> 2;
  const int q4log = (mcols == 32) ? 3 : 2;
  const int nel = mcols * q4;
  const float4* A4 = (const float4*)A;
  float4* G4 = (float4*)G;
  for (int e = tid; e < nel; e += BS) {
    const int c2q = e & (q4 - 1);
    const int c1 = e >> q4log;
    float ax = 0.f, ay = 0.f, az = 0.f, aw = 0.f;
    for (int r = 0; r < nrows; ++r) {
      const float a1 = A[r * 36 + c1];
      const float4 a2 = A4[r * 9 + c2q];
      ax += a1 * a2.x; ay += a1 * a2.y; az += a1 * a2.z; aw += a1 * a2.w;
    }
    float4* gp = G4 + c1 * 9 + c2q;
    if (init) { float4 o; o.x = ax; o.y = ay; o.z = az; o.w = aw; *gp = o; }
    else { float4 o = *gp; o.x += ax; o.y += ay; o.z += az; o.w += aw; *gp = o; }
  }
  __syncthreads();
}

// absorb column i1 of row j into BIGT[(rr-rr0)*dbw+db][ua] (stride 36), rr in [rr0,rr1)
__device__ __forceinline__ void absorb_T(const float* __restrict__ Tg, const float* __restrict__ poolS,
    float* __restrict__ BIGT, float* __restrict__ ATile, const int* __restrict__ xi,
    int i1, int j, int U, int Dd, int rr0, int rr1, int tid)
{
  const int bd = (i1 == 5) ? 1 : 4;
  const int dbw = Dd * bd;
  const int mt_ = U * 4;
  const int ph = xi[i1 * 6 + j];
  const float* tb = Tg + (size_t)(i1 * 6 + j) * 512;
  for (int e = tid; e < 256; e += BS) ATile[e] = tb[e * 2 + ph];
  __syncthreads();
  const int mlog = (mt_ == 32) ? 5 : 4;
  const int dblog = 31 - __clz(dbw);
  const int bdlog = (bd == 4) ? 2 : 0;
  const int nel = mt_ * dbw * (rr1 - rr0);
  for (int e = tid; e < nel; e += BS) {
    const int ua = e & (mt_ - 1);
    const int db = (e >> mlog) & (dbw - 1);
    const int rr = rr0 + (e >> (mlog + dblog));
    const int u = ua >> 2, a = ua & 3;
    const int d_ = db >> bdlog, b = db & (bd - 1);
    const float* op = poolS + u * 33 + d_;
    const float4 av = *(const float4*)(ATile + a * 64 + rr * 16 + b * 4);
    BIGT[((rr - rr0) * dbw + db) * 36 + ua] = op[0] * av.x + op[8] * av.y + op[16] * av.z + op[24] * av.w;
  }
  __syncthreads();
}

// ============ kernel 2: one sample per 256-thread (4-wave) workgroup ============
__global__ __launch_bounds__(256, 4) void peps_kernel(
    const float* __restrict__ Tg, const int* __restrict__ x,
    float* __restrict__ proj, float* __restrict__ out)
{
  __shared__ __align__(16) float pool[6 * 264];   // [i][u<=8 stride33][x=4 stride8][d<=8]
  __shared__ __align__(16) float CUR[1152];       // mt: rows (u*4+rr)<=32, stride 36
  __shared__ __align__(16) float BIGT[2304];      // mb^T half: rows <=64, stride 36
  __shared__ __align__(16) float GbM[1152];       // Gb (or Gt); m-path: Gb@0, Gt@576
  __shared__ __align__(16) float TM[1152];        // T / R2@0+V@576 / eigvecs V
  __shared__ __align__(16) float GM[1152];        // G / H in SEAT space
  __shared__ __align__(16) float ATile[256];
  __shared__ __align__(16) float PdL[256], PuL[256];  // [mrow][8]
  __shared__ float red[4];
  __shared__ int isel[8];
  __shared__ float sinvv[8], sdiv[8];
  __shared__ int xi[36];
  __shared__ float vvec[36], vvec2[36];

  const int s = blockIdx.x;
  const int tid = threadIdx.x;
  if (tid < 36) xi[tid] = x[s * 36 + tid];
  __syncthreads();

  for (int sweep = 0; sweep < 2; ++sweep) {
    // --- init boundary MPS from row j=0 ---
    for (int i2 = 0; i2 < 6; ++i2) {
      const int ad = (i2 == 0) ? 1 : 4, bd = (i2 == 5) ? 1 : 4;
      const int bdlog = (bd == 4) ? 2 : 0;
      const int ph = xi[i2 * 6];
      const float* tb = Tg + (size_t)(i2 * 6) * 512;
      const int nel = ad * 4 * bd;
      for (int e = tid; e < nel; e += BS) {
        const int b = e & (bd - 1);
        const int rr = (e >> bdlog) & 3;
        const int a = e >> (bdlog + 2);
        pool[i2 * 264 + a * 33 + rr * 8 + b] = tb[(a * 64 + rr * 16 + b * 4) * 2 + ph];
      }
    }
    __syncthreads();

    for (int j = 1; j <= 4; ++j) {
      const int jj = (j > 1) ? 1 : 0;
      // absorb column 0 into CUR (4 rows x 16 cols)
      {
        const int ph = xi[j];          // site (0,j)
        const float* tb = Tg + (size_t)j * 512;
        for (int e = tid; e < 256; e += BS) ATile[e] = tb[e * 2 + ph];
        __syncthreads();
        for (int e = tid; e < 64; e += BS) {
          const int db = e & 15;
          const int rr = e >> 4;
          const int d_ = db >> 2, b = db & 3;
          const float* op = pool + d_;  // slot 0, u=0
          const float4 av = *(const float4*)(ATile + rr * 16 + b * 4);  // a=0
          CUR[rr * 36 + db] = op[0] * av.x + op[8] * av.y + op[16] * av.z + op[24] * av.w;
        }
        __syncthreads();
      }

      for (int i = 0; i < 5; ++i) {
        const int m = g_mtab[jj][i], cb = g_cbtab[i], ucur = g_ucurtab[i], dn = g_dntab[jj][i];
        const int p = ucur * 4, path = g_path[jj][i];
        const int U1 = g_uprev[jj][i + 1], Dd1 = g_dprev[jj][i + 1];
        const bool two = (dn == 32);
        const int cblog = (cb == 8) ? 3 : 2;
        const int mq4 = m >> 2;
        float* projb = proj + (size_t)s * 6400 + g_offtab[j - 1][i];

        if (sweep == 0) {
          if (path == 2) {
            // ---- q-side (i=4): G = mb^T Gt mb (4x4), seat-permuted write ----
            absorb_T(Tg, pool + (i + 1) * 264, BIGT, ATile, xi, i + 1, j, U1, Dd1, 0, 4, tid);
            gram_cols(GbM, CUR, p, m, true, tid);   // Gt (16x16)
            for (int e = tid; e < 64; e += BS) {    // T1 = Gt*mb (16x4)
              const int r = e & 3, k = e >> 2;
              float acc = 0.f;
              const float4* G4 = (const float4*)GbM;
              const float4* B4 = (const float4*)BIGT;
              for (int lq = 0; lq < 4; ++lq) {
                const float4 g = G4[k * 9 + lq], b = B4[r * 9 + lq];
                acc += g.x * b.x + g.y * b.y + g.z * b.z + g.w * b.w;
              }
              TM[k * 36 + r] = acc;
            }
            __syncthreads();
            for (int e = tid; e < 16; e += BS) {    // G = mb^T * T1 (4x4)
              const int c = e & 3, r = e >> 2;
              float acc = 0.f;
              for (int k = 0; k < 16; ++k) acc += BIGT[r * 36 + k] * TM[k * 36 + c];
              GM[seatof(r, 4) * 36 + seatof(c, 4)] = acc;
            }
            __syncthreads();
            jacobi_pb<4>(GM, TM + 576, tid);
          } else if (path == 0) {
            // ---- p-side: G = mt Gb mt^T (p x p), seat-permuted write ----
            if (!two) {
              absorb_T(Tg, pool + (i + 1) * 264, BIGT, ATile, xi, i + 1, j, U1, Dd1, 0, 4, tid);
              gram_cols(GbM, BIGT, 4 * dn, m, true, tid);
            } else {
              absorb_T(Tg, pool + (i + 1) * 264, BIGT, ATile, xi, i + 1, j, U1, Dd1, 0, 2, tid);
              gram_cols(GbM, BIGT, 2 * dn, m, true, tid);
              absorb_T(Tg, pool + (i + 1) * 264, BIGT, ATile, xi, i + 1, j, U1, Dd1, 2, 4, tid);
              gram_cols(GbM, BIGT, 2 * dn, m, false, tid);
            }
            const int q4log = (m == 32) ? 3 : 2;
            for (int e = tid; e < p * mq4; e += BS) {  // T = mt*Gb (p x m)
              const int lq = e & (mq4 - 1), pr = e >> q4log;
              float ax = 0.f, ay = 0.f, az = 0.f, aw = 0.f;
              const float4* G4 = (const float4*)GbM;
              for (int k = 0; k < m; ++k) {
                const float a1 = CUR[pr * 36 + k];
                const float4 g = G4[k * 9 + lq];
                ax += a1 * g.x; ay += a1 * g.y; az += a1 * g.z; aw += a1 * g.w;
              }
              float4 o; o.x = ax; o.y = ay; o.z = az; o.w = aw;
              ((float4*)TM)[pr * 9 + lq] = o;
            }
            __syncthreads();
            const int plog = (p == 32) ? 5 : ((p == 16) ? 4 : 2);
            for (int e = tid; e < p * p; e += BS) {    // G = T*mt^T (p x p)
              const int pc = e & (p - 1), pr = e >> plog;
              float acc = 0.f;
              const float4* T4 = (const float4*)TM;
              const float4* C4 = (const float4*)CUR;
              for (int lq = 0; lq < mq4; ++lq) {
                const float4 t = T4[pr * 9 + lq], c = C4[pc * 9 + lq];
                acc += t.x * c.x + t.y * c.y + t.z * c.z + t.w * c.w;
              }
              GM[seatof(pr, p) * 36 + seatof(pc, p)] = acc;
            }
            __syncthreads();
            if (p == 4)       jacobi_pb<4>(GM, TM, tid);
            else if (p == 16) jacobi_pb<16>(GM, TM, tid);
            else              jacobi_pb<32>(GM, TM, tid);
          } else {
            // ---- m-side (j=1, i=2,3): Gt, Gb, chol(Gb), H = R2 Gt R2^T (16x16), seat write ----
            absorb_T(Tg, pool + (i + 1) * 264, BIGT, ATile, xi, i + 1, j, U1, Dd1, 0, 4, tid);
            gram_cols(GbM + 576, CUR, p, m, true, tid);     // Gt
            gram_cols(GbM, BIGT, 4 * dn, m, true, tid);     // Gb
            // cholesky Gb -> R2 (TM[0:576]) with zero-skip
            if (tid < 64) {
              float v_ = (tid < 16) ? GbM[tid * 37] : -3.0e38f;
              for (int mk = 32; mk; mk >>= 1) v_ = fmaxf(v_, __shfl_xor(v_, mk));
              if (tid == 0) red[0] = v_;
            }
            __syncthreads();
            const float thr = 1e-10f * red[0] + 1e-35f;
            for (int k = 0; k < 16; ++k) {
              const float dk = GbM[k * 37];
              const float rs = (dk > thr) ? (1.0f / sqrtf(dk)) : 0.0f;
              if (tid < 16) TM[k * 36 + tid] = GbM[k * 36 + tid] * rs;
              __syncthreads();
              const int rows = 15 - k;
              for (int e = tid; e < rows * 16; e += BS) {
                const int ii = k + 1 + (e >> 4), jc = e & 15;
                GbM[ii * 36 + jc] -= TM[k * 36 + ii] * TM[k * 36 + jc];
              }
              __syncthreads();
            }
            for (int e = tid; e < 64; e += BS) {   // T1 = R2*Gt -> TM+576
              const int jq = e & 3, k = e >> 2;
              float ax = 0.f, ay = 0.f, az = 0.f, aw = 0.f;
              const float4* Gt4 = (const float4*)(GbM + 576);
              for (int l = 0; l < 16; ++l) {
                const float r2 = TM[k * 36 + l];
                const float4 g = Gt4[l * 9 + jq];
                ax += r2 * g.x; ay += r2 * g.y; az += r2 * g.z; aw += r2 * g.w;
              }
              float4 o; o.x = ax; o.y = ay; o.z = az; o.w = aw;
              ((float4*)(TM + 576))[k * 9 + jq] = o;
            }
            __syncthreads();
            for (int e = tid; e < 256; e += BS) {  // H = T1*R2^T -> GM (seat space)
              const int k2 = e & 15, k = e >> 4;
              float acc = 0.f;
              const float4* T14 = (const float4*)(TM + 576);
              const float4* R24 = (const float4*)TM;
              for (int lq = 0; lq < 4; ++lq) {
                const float4 t = T14[k * 9 + lq], r = R24[k2 * 9 + lq];
                acc += t.x * r.x + t.y * r.y + t.z * r.z + t.w * r.w;
              }
              GM[seatof(k, 16) * 36 + seatof(k2, 16)] = acc;
            }
            __syncthreads();
            jacobi_pb<16>(GM, TM + 576, tid);
          }

          // ---- top-cb selection + scales (seat labels opaque; wave 0 only) ----
          const int N = (path == 2) ? 4 : ((path == 1) ? 16 : p);
          if (tid < 64) {
            float v_ = (tid < N) ? GM[tid * 37] : -3.0e38f;
            int ix = tid;
            for (int t = 0; t < cb; ++t) {
              float bv = v_; int bi = ix;
              for (int mk = 32; mk; mk >>= 1) {
                const float ov = __shfl_xor(bv, mk);
                const int oi = __shfl_xor(bi, mk);
                if (ov > bv || (ov == bv && oi < bi)) { bv = ov; bi = oi; }
              }
              if (tid == 0) isel[t] = bi;
              if (ix == bi) v_ = -3.0e38f;
            }
          }
          __syncthreads();
          if (tid < cb) {
            const float lam = GM[isel[tid] * 37];
            const float s_ = sqrtf(fmaxf(lam, 0.0f));
            sinvv[tid] = 1.0f / sqrtf(s_ + 1e-12f);
            sdiv[tid]  = 1.0f / fmaxf(s_, 1e-25f);
          }
          __syncthreads();

          // ---- projectors (V rows are G-space; columns indexed by seat isel) ----
          if (path == 0) {
            // Pu = mt^T U sinv ; Pd = Gb Pu / s   (U cols in TM)
            for (int e = tid; e < m * cb; e += BS) {
              const int k = e & (cb - 1), mrow = e >> cblog;
              const int a = isel[k];
              float acc = 0.f;
              for (int pr = 0; pr < p; ++pr) acc += CUR[pr * 36 + mrow] * TM[pr * 36 + a];
              PuL[mrow * 8 + k] = acc * sinvv[k];
            }
            __syncthreads();
            for (int e = tid; e < m * cb; e += BS) {
              const int k = e & (cb - 1), mrow = e >> cblog;
              float acc = 0.f;
              for (int l = 0; l < m; ++l) acc += GbM[mrow * 36 + l] * PuL[l * 8 + k];
              PdL[mrow * 8 + k] = acc * sdiv[k];
            }
            __syncthreads();
          } else if (path == 2) {
            // Pd = mb V sinv ; Pu = Gt Pd / s   (V in TM+576, Gt in GbM)
            for (int e = tid; e < m * cb; e += BS) {
              const int k = e & (cb - 1), mrow = e >> cblog;
              const int a = isel[k];
              float acc = 0.f;
              for (int r = 0; r < 4; ++r) acc += BIGT[r * 36 + mrow] * TM[576 + r * 36 + a];
              PdL[mrow * 8 + k] = acc * sinvv[k];
            }
            __syncthreads();
            for (int e = tid; e < m * cb; e += BS) {
              const int k = e & (cb - 1), mrow = e >> cblog;
              float acc = 0.f;
              for (int l = 0; l < m; ++l) acc += GbM[mrow * 36 + l] * PdL[l * 8 + k];
              PuL[mrow * 8 + k] = acc * sdiv[k];
            }
            __syncthreads();
          } else {
            // Pd = R2^T V sinv ; Pu = Gt Pd / s  (R2 in TM[0:576], V in TM+576, Gt in GbM+576)
            for (int e = tid; e < m * cb; e += BS) {
              const int k = e & (cb - 1), mrow = e >> cblog;
              const int a = isel[k];
              float acc = 0.f;
              for (int t = 0; t < 16; ++t) acc += TM[t * 36 + mrow] * TM[576 + t * 36 + a];
              PdL[mrow * 8 + k] = acc * sinvv[k];
            }
            __syncthreads();
            for (int e = tid; e < m * cb; e += BS) {
              const int k = e & (cb - 1), mrow = e >> cblog;
              float acc = 0.f;
              for (int l = 0; l < m; ++l) acc += GbM[576 + mrow * 36 + l] * PdL[l * 8 + k];
              PuL[mrow * 8 + k] = acc * sdiv[k];
            }
            __syncthreads();
          }
          // store perturbed projectors (ws slot preloaded with ETA*mlp)
          for (int e = tid; e < m * cb; e += BS)
            projb[e] += PdL[(e >> cblog) * 8 + (e & (cb - 1))];
          for (int e = tid; e < m * cb; e += BS)
            projb[m * cb + e] += PuL[(e >> cblog) * 8 + (e & (cb - 1))];
        } else {
          // ---- sweep 2: load perturbed projectors + stage mb (B-half for two-pass) ----
          for (int e = tid; e < m * cb; e += BS)
            PdL[(e >> cblog) * 8 + (e & (cb - 1))] = projb[e];
          for (int e = tid; e < m * cb; e += BS)
            PuL[(e >> cblog) * 8 + (e & (cb - 1))] = projb[m * cb + e];
          __syncthreads();
          if (!two) absorb_T(Tg, pool + (i + 1) * 264, BIGT, ATile, xi, i + 1, j, U1, Dd1, 0, 4, tid);
          else      absorb_T(Tg, pool + (i + 1) * 264, BIGT, ATile, xi, i + 1, j, U1, Dd1, 2, 4, tid);
        }

        // ---- common: Bn[i] = Tt*Pd -> pool[i]; Bn[i+1] = Pu applied to mb -> CUR (or pool[5]) ----
        {
          const int nel = ucur * 4 * cb;
          const float4* C4 = (const float4*)CUR;
          for (int e = tid; e < nel; e += BS) {
            const int cc = e & (cb - 1);
            const int rr = (e >> cblog) & 3;
            const int u = e >> (cblog + 2);
            const int row = u * 4 + rr;
            float acc = 0.f;
            for (int mq = 0; mq < mq4; ++mq) {
              const float4 cv = C4[row * 9 + mq];
              acc += cv.x * PdL[(mq * 4 + 0) * 8 + cc] + cv.y * PdL[(mq * 4 + 1) * 8 + cc]
                   + cv.z * PdL[(mq * 4 + 2) * 8 + cc] + cv.w * PdL[(mq * 4 + 3) * 8 + cc];
            }
            pool[i * 264 + u * 33 + rr * 8 + cc] = acc;
          }
          __syncthreads();

          const int dnlog = 31 - __clz(dn);
          auto bn1 = [&](int rr0, int nloc) {
            const int ne2 = cb * nloc * dn;
            const float4* B4 = (const float4*)BIGT;
            for (int e = tid; e < ne2; e += BS) {
              const int dd = e & (dn - 1);
              const int t = e >> dnlog;
              const int rrL = t & (nloc - 1);
              const int cc = t >> ((nloc == 4) ? 2 : 1);
              const int row = rrL * dn + dd;
              float acc = 0.f;
              for (int mq = 0; mq < mq4; ++mq) {
                const float4 bv = B4[row * 9 + mq];
                acc += bv.x * PuL[(mq * 4 + 0) * 8 + cc] + bv.y * PuL[(mq * 4 + 1) * 8 + cc]
                     + bv.z * PuL[(mq * 4 + 2) * 8 + cc] + bv.w * PuL[(mq * 4 + 3) * 8 + cc];
              }
              if (i < 4) CUR[(cc * 4 + rr0 + rrL) * 36 + dd] = acc;
              else       pool[5 * 264 + cc * 33 + (rr0 + rrL) * 8] = acc;
            }
            __syncthreads();
          };
          if (!two) {
            bn1(0, 4);
          } else {
            bn1(2, 2);
            absorb_T(Tg, pool + (i + 1) * 264, BIGT, ATile, xi, i + 1, j, U1, Dd1, 0, 2, tid);
            bn1(0, 2);
          }
        }
      }
    }

    if (sweep == 1) {
      // ---- finalize: scalar = prod_i C_i ----
      if (tid == 0) vvec[0] = 1.0f;
      __syncthreads();
      for (int i = 0; i < 6; ++i) {
        const int ad = (i == 0) ? 1 : 4, bd = (i == 5) ? 1 : 4;
        const int adlog = (ad == 4) ? 2 : 0, bdlog = (bd == 4) ? 2 : 0;
        const int rows = g_ufin[i] * ad, cols = g_dfin[i] * bd;
        const int clog = 31 - __clz(cols);
        const int ph = xi[i * 6 + 5];
        const float* tb = Tg + (size_t)(i * 6 + 5) * 512;
        for (int e = tid; e < 256; e += BS) ATile[e] = tb[e * 2 + ph];
        __syncthreads();
        for (int e = tid; e < rows * cols; e += BS) {
          const int col = e & (cols - 1);
          const int ua = e >> clog;
          const int u = ua >> adlog, a = ua & (ad - 1);
          const int d_ = col >> bdlog, b = col & (bd - 1);
          const float* fb = pool + i * 264 + u * 33 + d_;
          const float4 av = *(const float4*)(ATile + a * 64 + b * 4);  // R = 0 slice
          GM[ua * 36 + col] = fb[0] * av.x + fb[8] * av.y + fb[16] * av.z + fb[24] * av.w;
        }
        __syncthreads();
        if (tid < cols) {
          float acc = 0.f;
          for (int r_ = 0; r_ < rows; ++r_) acc += vvec[r_] * GM[r_ * 36 + tid];
          vvec2[tid] = acc;
        }
        __syncthreads();
        if (tid < cols) vvec[tid] = vvec2[tid];
        __syncthreads();
      }
      if (tid == 0) out[s] = vvec[0];
    }
  }
}

extern "C" void kernel_launch(void* const* d_in, const int* in_sizes, int n_in,
                              void* d_out, int out_size, void* d_ws, size_t ws_size,
                              hipStream_t stream) {
  const float* Tg = (const float*)d_in[0];
  const float* W1 = (const float*)d_in[1];
  const float* b1 = (const float*)d_in[2];
  const float* W2 = (const float*)d_in[3];
  const float* b2 = (const float*)d_in[4];
  const int*   x  = (const int*)d_in[5];
  float* out = (float*)d_out;
  float* proj = (float*)d_ws;   // 1024*6400 floats: ETA*mlp then += projectors
  (void)in_sizes; (void)n_in; (void)out_size; (void)ws_size;

  mlp_kernel<<<dim3(128), dim3(256), 0, stream>>>(W1, b1, W2, b2, x, proj);
  peps_kernel<<<dim3(1024), dim3(256), 0, stream>>>(Tg, x, proj, out);
}